// Round 6
// baseline (630.425 us; speedup 1.0000x reference)
//
#include <hip/hip_runtime.h>
#include <hip/hip_bf16.h>

// MultiheadBlockAttention: B=4, S=512, NB=32, D=512, H=8, dh=64.
// R6: SMUL=2 — one WG (8 waves) handles TWO (b,s) pairs; wave h == head h.
// Halves the per-work L2 weight stream (R5's limiter: 3.1 GB L2 reads ~ per-XCD
// L2 ceiling) and doubles MFMA per weight load.
// Projection order K^T -> Q^T -> V; K^T/Q^T stay in regs (packed C/D), V acc is
// packed per-tile then written (post-barrier) into per-wave V-buffers OVERLAID
// on the then-dead Xs staging region -> LDS stays 66 KB, 2 WG/CU.

#define NBD (32 * 512)
#define XS_STRIDE 516                    // shorts per X row = 1032 B
#define XS_BYTES (32 * XS_STRIDE * 2)    // 33024 B per (b,s) buffer

typedef __bf16 bf16x8 __attribute__((ext_vector_type(8)));
typedef float f32x16 __attribute__((ext_vector_type(16)));

__device__ __forceinline__ unsigned f2b(float f) {
  union { float f; unsigned u; } v;
  v.f = f;
  return (v.u + 0x7fffu + ((v.u >> 16) & 1u)) >> 16;
}

__device__ __forceinline__ f32x16 mfma32(uint4 a, uint4 b, f32x16 c) {
  union { uint4 u; bf16x8 v; } ua, ub;
  ua.u = a;
  ub.u = b;
  return __builtin_amdgcn_mfma_f32_32x32x16_bf16(ua.v, ub.v, c, 0, 0, 0);
}

// two ds_read_b64 (8-aligned base)
__device__ __forceinline__ uint4 ld_lds_64x2(const unsigned short* p, unsigned byteoff) {
  const char* c = (const char*)p;
  uint2 lo = *(const uint2*)(c + byteoff);
  uint2 hi = *(const uint2*)(c + byteoff + 8);
  uint4 r;
  r.x = lo.x; r.y = lo.y; r.z = hi.x; r.w = hi.y;
  return r;
}

// C/D packed frag -> A/B-frag k-slice [qb block]: cross-half exchange + select.
__device__ __forceinline__ uint4 frag_cd(const unsigned* CP, int qb, int half) {
  const unsigned s0 = __shfl_xor(CP[qb + 0], 32);
  const unsigned s1 = __shfl_xor(CP[qb + 1], 32);
  const unsigned s2 = __shfl_xor(CP[qb + 2], 32);
  const unsigned s3 = __shfl_xor(CP[qb + 3], 32);
  uint4 f;
  f.x = half ? s2 : CP[qb + 0];
  f.y = half ? s3 : CP[qb + 1];
  f.z = half ? CP[qb + 2] : s0;
  f.w = half ? CP[qb + 3] : s1;
  return f;
}

// Pack wq|wk|wv fragment-major bf16: uint4 index
//   m*32768 + tile*2048 + k*64 + half*32 + l31  holds W[tile*32+l31][k*16+half*8..+7]
__global__ void wconv_kernel(const float* __restrict__ wq,
                             const float* __restrict__ wk,
                             const float* __restrict__ wv,
                             uint4* __restrict__ out) {
  const int g = blockIdx.x * blockDim.x + threadIdx.x;  // 0..98303
  const int m = g >> 15;
  const int j = g & 32767;
  const int l31 = j & 31;
  const int half = (j >> 5) & 1;
  const int k = (j >> 6) & 31;
  const int tile = j >> 11;  // 0..15
  const float* src = (m == 0) ? wq : (m == 1) ? wk : wv;
  const float4* p = (const float4*)(src + (size_t)(tile * 32 + l31) * 512 + k * 16 + half * 8);
  float4 f0 = p[0], f1 = p[1];
  uint4 o;
  o.x = f2b(f0.x) | (f2b(f0.y) << 16);
  o.y = f2b(f0.z) | (f2b(f0.w) << 16);
  o.z = f2b(f1.x) | (f2b(f1.y) << 16);
  o.w = f2b(f1.z) | (f2b(f1.w) << 16);
  out[g] = o;
}

__global__ __launch_bounds__(512, 4)
void mhba_kernel(const float* __restrict__ q_in, const float* __restrict__ k_in,
                 const float* __restrict__ v_in, const float* __restrict__ mask,
                 const float* __restrict__ bq, const float* __restrict__ bk,
                 const float* __restrict__ bv,
                 const uint4* __restrict__ wpk,   // fragment-major bf16 weights
                 float* __restrict__ out_attn,    // [B,S,NB,D]
                 float* __restrict__ out_w) {     // [B,H,S,NB,NB]
  // Two X staging buffers (one per bs). After the V sweep + barrier this
  // region is dead and is overlaid with per-wave V-buffers / out_w scratch.
  __shared__ unsigned short Xs[2 * 32 * XS_STRIDE];  // 66048 B

  const int bs0 = blockIdx.x * 2;
  const int tid = threadIdx.x;  // 0..511
  const int lane = tid & 63;
  const int h = tid >> 6;       // wave == head
  const int l31 = lane & 31;
  const int half = lane >> 5;

  // m-loop: 0 = K^T (regs), 1 = Q^T (regs), 2 = V (packed regs -> LDS overlay)
  const float* srcG[3] = {k_in, q_in, v_in};

  unsigned KT[2][2][8], QT[2][2][8], VPk[2][2][8];

  const unsigned abase = (unsigned)(l31 * (XS_STRIDE * 2) + half * 16);

#pragma unroll
  for (int m = 0; m < 3; ++m) {
    __syncthreads();  // previous Xs readers done
    // stage X for both bs (f32 -> bf16)
#pragma unroll
    for (int j = 0; j < 2; ++j) {
      const float4* s4 = (const float4*)(srcG[m] + (size_t)(bs0 + j) * NBD);
#pragma unroll
      for (int i = 0; i < 8; ++i) {
        const int idx4 = i * 512 + tid;  // 128 float4 per row
        float4 f = s4[idx4];
        const int n = idx4 >> 7;
        const int k4 = idx4 & 127;
        uint2 u;
        u.x = f2b(f.x) | (f2b(f.y) << 16);
        u.y = f2b(f.z) | (f2b(f.w) << 16);
        *(uint2*)((char*)Xs + (j * XS_BYTES + n * (XS_STRIDE * 2) + k4 * 8)) = u;
      }
    }
    __syncthreads();

    const int wsel = (m == 0) ? 1 : (m == 1) ? 0 : 2;  // K<-wk, Q<-wq, V<-wv
#pragma unroll
    for (int t = 0; t < 2; ++t) {
      const uint4* wld = wpk + wsel * 32768 + (2 * h + t) * 2048 + half * 32 + l31;
      f32x16 acc0, acc1;
#pragma unroll
      for (int r = 0; r < 16; ++r) { acc0[r] = 0.0f; acc1[r] = 0.0f; }
#pragma unroll 8
      for (int k = 0; k < 32; ++k) {
        uint4 b = wld[k * 64];
        uint4 a0 = ld_lds_64x2(Xs, abase + (unsigned)k * 32);
        uint4 a1 = ld_lds_64x2(Xs, XS_BYTES + abase + (unsigned)k * 32);
        if (m <= 1) {  // transposed: A = W (features->regs), B = X (tokens->lanes)
          acc0 = mfma32(b, a0, acc0);
          acc1 = mfma32(b, a1, acc1);
        } else {       // normal: A = X (tokens->regs), B = W (features->lanes)
          acc0 = mfma32(a0, b, acc0);
          acc1 = mfma32(a1, b, acc1);
        }
      }
      if (m == 0) {
#pragma unroll
        for (int q = 0; q < 8; ++q) {
          const int n0 = ((2 * q) & 3) + 8 * (q >> 1) + 4 * half;  // feature idx
          float2 bb = *(const float2*)(bk + h * 64 + t * 32 + n0);
          KT[0][t][q] = f2b(acc0[2 * q] + bb.x) | (f2b(acc0[2 * q + 1] + bb.y) << 16);
          KT[1][t][q] = f2b(acc1[2 * q] + bb.x) | (f2b(acc1[2 * q + 1] + bb.y) << 16);
        }
      } else if (m == 1) {
#pragma unroll
        for (int q = 0; q < 8; ++q) {
          const int n0 = ((2 * q) & 3) + 8 * (q >> 1) + 4 * half;
          float2 bb = *(const float2*)(bq + h * 64 + t * 32 + n0);
          QT[0][t][q] = f2b(acc0[2 * q] + bb.x) | (f2b(acc0[2 * q + 1] + bb.y) << 16);
          QT[1][t][q] = f2b(acc1[2 * q] + bb.x) | (f2b(acc1[2 * q + 1] + bb.y) << 16);
        }
      } else {
        const float bc = bv[h * 64 + t * 32 + l31];
#pragma unroll
        for (int q = 0; q < 8; ++q) {
          VPk[0][t][q] = f2b(acc0[2 * q] + bc) | (f2b(acc0[2 * q + 1] + bc) << 16);
          VPk[1][t][q] = f2b(acc1[2 * q] + bc) | (f2b(acc1[2 * q + 1] + bc) << 16);
        }
      }
    }
  }

  // All waves done reading Xs -> overlay per-wave V-buffers on it.
  __syncthreads();
  // V-buf: wave h, bs j at byte h*8192 + j*4096; rows = token n (128 B),
  // cols = local feature (2 B), XOR ((n&7)<<4) swizzle.
#pragma unroll
  for (int j = 0; j < 2; ++j) {
    char* vb = (char*)Xs + h * 8192 + j * 4096;
#pragma unroll
    for (int t = 0; t < 2; ++t)
#pragma unroll
      for (int q = 0; q < 8; ++q) {
        const int n0 = ((2 * q) & 3) + 8 * (q >> 1) + 4 * half;  // token row (even)
        const unsigned col = (unsigned)((t * 32 + l31) * 2);
        const unsigned pv = VPk[j][t][q];
        *(unsigned short*)(vb + ((n0 * 128 + col) ^ ((unsigned)(n0 & 7) << 4))) =
            (unsigned short)(pv & 0xffff);
        *(unsigned short*)(vb + (((n0 + 1) * 128 + col) ^ ((unsigned)((n0 + 1) & 7) << 4))) =
            (unsigned short)(pv >> 16);
      }
  }

  // ---------------- attention per bs (barrier-free, per-wave) ----------------
#pragma unroll
  for (int j = 0; j < 2; ++j) {
    const int bsj = bs0 + j;

    // S^T = K * Q^T
    f32x16 lg;
#pragma unroll
    for (int r = 0; r < 16; ++r) lg[r] = 0.0f;
#pragma unroll
    for (int kk = 0; kk < 4; ++kk) {
      uint4 ka = frag_cd(KT[j][kk >> 1], (kk & 1) * 4, half);
      uint4 qf = frag_cd(QT[j][kk >> 1], (kk & 1) * 4, half);
      lg = mfma32(ka, qf, lg);
    }

    // softmax over keys (lane = query n, regs = key m), additive mask
    const float* mrow = mask + (size_t)bsj * 32;
    float w[16];
#pragma unroll
    for (int q = 0; q < 8; ++q) {
      const int mm0 = ((2 * q) & 3) + 8 * (q >> 1) + 4 * half;
      float2 mk = *(const float2*)(mrow + mm0);
      w[2 * q] = lg[2 * q] * 0.125f + mk.x;
      w[2 * q + 1] = lg[2 * q + 1] * 0.125f + mk.y;
    }
    float mx = w[0];
#pragma unroll
    for (int r = 1; r < 16; ++r) mx = fmaxf(mx, w[r]);
    mx = fmaxf(mx, __shfl_xor(mx, 32));
    float ss = 0.0f;
#pragma unroll
    for (int r = 0; r < 16; ++r) {
      w[r] = __expf(w[r] - mx);
      ss += w[r];
    }
    ss += __shfl_xor(ss, 32);
    const float inv = __frcp_rn(ss);
#pragma unroll
    for (int r = 0; r < 16; ++r) w[r] *= inv;

    // pack P (lane = query n, reg pairs = key rows)
    unsigned PP[8];
#pragma unroll
    for (int q = 0; q < 8; ++q)
      PP[q] = f2b(w[2 * q]) | (f2b(w[2 * q + 1]) << 16);

    // O = P * V  (B-frags: 8 u16 reads per frag from swizzled V-buf)
    const char* vb = (const char*)Xs + h * 8192 + j * 4096;
    f32x16 o0, o1;
#pragma unroll
    for (int r = 0; r < 16; ++r) { o0[r] = 0.0f; o1[r] = 0.0f; }
#pragma unroll
    for (int kk = 0; kk < 2; ++kk) {
      uint4 pa = frag_cd(PP, 4 * kk, half);
      unsigned pk0[4] = {0, 0, 0, 0}, pk1[4] = {0, 0, 0, 0};
#pragma unroll
      for (int jj = 0; jj < 8; ++jj) {
        const int mr = kk * 16 + half * 8 + jj;
        const unsigned sw = (unsigned)(mr & 7) << 4;
        const unsigned v0 = *(const unsigned short*)(vb + ((mr * 128 + l31 * 2) ^ sw));
        const unsigned v1 = *(const unsigned short*)(vb + ((mr * 128 + 64 + l31 * 2) ^ sw));
        pk0[jj >> 1] |= v0 << ((jj & 1) * 16);
        pk1[jj >> 1] |= v1 << ((jj & 1) * 16);
      }
      uint4 b0, b1;
      b0.x = pk0[0]; b0.y = pk0[1]; b0.z = pk0[2]; b0.w = pk0[3];
      b1.x = pk1[0]; b1.y = pk1[1]; b1.z = pk1[2]; b1.w = pk1[3];
      o0 = mfma32(pa, b0, o0);
      o1 = mfma32(pa, b1, o1);
    }

    // out_w: V-buf[j] is dead now -> reuse as swizzled f32 scratch (4 KB)
    asm volatile("" ::: "memory");
    char* sc = (char*)Xs + h * 8192 + j * 4096;
#pragma unroll
    for (int r = 0; r < 16; ++r) {
      const int mm = (r & 3) + 8 * (r >> 2) + 4 * half;  // key idx
      *(float*)(sc + ((l31 * 128 + mm * 4) ^ ((unsigned)(l31 & 7) << 4))) = w[r];
    }
    const int b = bsj >> 9;
    const int s = bsj & 511;
    float* wout = out_w + ((size_t)((b * 8 + h) * 512 + s)) * 1024;
#pragma unroll
    for (int jj = 0; jj < 16; ++jj) {
      const int n = 2 * jj + half;
      wout[n * 32 + l31] =
          *(const float*)(sc + ((n * 128 + l31 * 4) ^ ((unsigned)(n & 7) << 4)));
    }

    // output: lane col d = t*32+l31 of head h, rows n in regs
    float* obase = out_attn + (size_t)bsj * NBD + h * 64 + l31;
#pragma unroll
    for (int r = 0; r < 16; ++r) {
      const int n = (r & 3) + 8 * (r >> 2) + 4 * half;
      obase[n * 512] = o0[r];
      obase[n * 512 + 32] = o1[r];
    }
  }
}

extern "C" void kernel_launch(void* const* d_in, const int* in_sizes, int n_in,
                              void* d_out, int out_size, void* d_ws, size_t ws_size,
                              hipStream_t stream) {
  const float* q    = (const float*)d_in[0];
  const float* k    = (const float*)d_in[1];
  const float* v    = (const float*)d_in[2];
  const float* mask = (const float*)d_in[3];
  const float* wq   = (const float*)d_in[4];
  const float* bq   = (const float*)d_in[5];
  const float* wk   = (const float*)d_in[6];
  const float* bk   = (const float*)d_in[7];
  const float* wv   = (const float*)d_in[8];
  const float* bv   = (const float*)d_in[9];

  uint4* wpk = (uint4*)d_ws;  // 3*32768 uint4 = 1.5 MB fragment-major weights
  float* out_attn = (float*)d_out;
  float* out_w = out_attn + (size_t)4 * 512 * 32 * 512;

  wconv_kernel<<<384, 256, 0, stream>>>(wq, wk, wv, wpk);
  mhba_kernel<<<1024, 512, 0, stream>>>(q, k, v, mask, bq, bk, bv, wpk,
                                        out_attn, out_w);
}

// Round 7
// 350.330 us; speedup vs baseline: 1.7995x; 1.7995x over previous
//
#include <hip/hip_runtime.h>
#include <hip/hip_bf16.h>

// MultiheadBlockAttention: B=4, S=512, NB=32, D=512, H=8, dh=64.
// R7: SMUL=2 at launch_bounds(512,2) — 256 unified regs/thread, 1 WG/CU.
//   - one WG (8 waves) = TWO (b,s) pairs; wave h == head h; each weight
//     fragment load feeds 2 MFMAs (halves R5's 3.1GB L2 weight stream)
//   - double-buffered X staging (2 x 66KB LDS): loads for matrix m+1 issued
//     into regs BEFORE compute of m, written to the other buffer after ->
//     3 barriers total, global latency hidden under 128-MFMA compute phases
//   - K^T/Q^T/V all in registers (96 packed + 32 acc + 64 in-flight < 256)
//   - attention per bs fully in-register (R6-verified math), out_w transposed
//     through scratch overlaid on the dead Q-staging buffer.

#define NBD (32 * 512)
#define XS_STRIDE 516                  // shorts per X row = 1032 B
#define XS_BYTES (32 * XS_STRIDE * 2)  // 33024 B per (b,s) slice

typedef __bf16 bf16x8 __attribute__((ext_vector_type(8)));
typedef float f32x16 __attribute__((ext_vector_type(16)));

__device__ __forceinline__ unsigned f2b(float f) {
  union { float f; unsigned u; } v;
  v.f = f;
  return (v.u + 0x7fffu + ((v.u >> 16) & 1u)) >> 16;
}

__device__ __forceinline__ f32x16 mfma32(uint4 a, uint4 b, f32x16 c) {
  union { uint4 u; bf16x8 v; } ua, ub;
  ua.u = a;
  ub.u = b;
  return __builtin_amdgcn_mfma_f32_32x32x16_bf16(ua.v, ub.v, c, 0, 0, 0);
}

// two ds_read_b64 (8-aligned base)
__device__ __forceinline__ uint4 ld_lds_64x2(const unsigned short* p, unsigned byteoff) {
  const char* c = (const char*)p;
  uint2 lo = *(const uint2*)(c + byteoff);
  uint2 hi = *(const uint2*)(c + byteoff + 8);
  uint4 r;
  r.x = lo.x; r.y = lo.y; r.z = hi.x; r.w = hi.y;
  return r;
}

// C/D packed frag -> A/B-frag k-slice [qb block]: cross-half exchange + select.
__device__ __forceinline__ uint4 frag_cd(const unsigned* CP, int qb, int half) {
  const unsigned s0 = __shfl_xor(CP[qb + 0], 32);
  const unsigned s1 = __shfl_xor(CP[qb + 1], 32);
  const unsigned s2 = __shfl_xor(CP[qb + 2], 32);
  const unsigned s3 = __shfl_xor(CP[qb + 3], 32);
  uint4 f;
  f.x = half ? s2 : CP[qb + 0];
  f.y = half ? s3 : CP[qb + 1];
  f.z = half ? CP[qb + 2] : s0;
  f.w = half ? CP[qb + 3] : s1;
  return f;
}

// Pack wq|wk|wv fragment-major bf16: uint4 index
//   m*32768 + tile*2048 + k*64 + half*32 + l31  holds W[tile*32+l31][k*16+half*8..+7]
__global__ void wconv_kernel(const float* __restrict__ wq,
                             const float* __restrict__ wk,
                             const float* __restrict__ wv,
                             uint4* __restrict__ out) {
  const int g = blockIdx.x * blockDim.x + threadIdx.x;  // 0..98303
  const int m = g >> 15;
  const int j = g & 32767;
  const int l31 = j & 31;
  const int half = (j >> 5) & 1;
  const int k = (j >> 6) & 31;
  const int tile = j >> 11;  // 0..15
  const float* src = (m == 0) ? wq : (m == 1) ? wk : wv;
  const float4* p = (const float4*)(src + (size_t)(tile * 32 + l31) * 512 + k * 16 + half * 8);
  float4 f0 = p[0], f1 = p[1];
  uint4 o;
  o.x = f2b(f0.x) | (f2b(f0.y) << 16);
  o.y = f2b(f0.z) | (f2b(f0.w) << 16);
  o.z = f2b(f1.x) | (f2b(f1.y) << 16);
  o.w = f2b(f1.z) | (f2b(f1.w) << 16);
  out[g] = o;
}

__global__ __launch_bounds__(512, 2)
void mhba_kernel(const float* __restrict__ q_in, const float* __restrict__ k_in,
                 const float* __restrict__ v_in, const float* __restrict__ mask,
                 const float* __restrict__ bq, const float* __restrict__ bk,
                 const float* __restrict__ bv,
                 const uint4* __restrict__ wpk,   // fragment-major bf16 weights
                 float* __restrict__ out_attn,    // [B,S,NB,D]
                 float* __restrict__ out_w) {     // [B,H,S,NB,NB]
  // Two X-pair staging buffers: buf p at p*2*XS_BYTES, bs j within at j*XS_BYTES.
  __shared__ unsigned short Xs[2 * 2 * 32 * XS_STRIDE];  // 132096 B

  const int bs0 = blockIdx.x * 2;
  const int tid = threadIdx.x;  // 0..511
  const int lane = tid & 63;
  const int h = tid >> 6;       // wave == head
  const int l31 = lane & 31;
  const int half = lane >> 5;

  unsigned short* bufA = Xs;
  unsigned short* bufB = Xs + 2 * 32 * XS_STRIDE;

  unsigned KT[2][2][8], QT[2][2][8], VP[2][2][8];
  const unsigned abase = (unsigned)(l31 * (XS_STRIDE * 2) + half * 16);

  float4 st[16];  // in-flight staging registers (2 bs x 8 float4)

#define LOADS(SRC)                                                        \
  {                                                                       \
    _Pragma("unroll") for (int j = 0; j < 2; ++j) {                       \
      const float4* s4 = (const float4*)((SRC) + (size_t)(bs0 + j) * NBD);\
      _Pragma("unroll") for (int i = 0; i < 8; ++i)                       \
        st[j * 8 + i] = s4[i * 512 + tid];                                \
    }                                                                     \
  }

#define WRITE(BUF)                                                        \
  {                                                                       \
    _Pragma("unroll") for (int j = 0; j < 2; ++j) {                       \
      _Pragma("unroll") for (int i = 0; i < 8; ++i) {                     \
        const int idx4 = i * 512 + tid;                                   \
        const int n = idx4 >> 7;                                          \
        const int k4 = idx4 & 127;                                        \
        float4 f = st[j * 8 + i];                                         \
        uint2 u;                                                          \
        u.x = f2b(f.x) | (f2b(f.y) << 16);                                \
        u.y = f2b(f.z) | (f2b(f.w) << 16);                                \
        *(uint2*)((char*)(BUF) + (j * XS_BYTES + n * (XS_STRIDE * 2) + k4 * 8)) = u; \
      }                                                                   \
    }                                                                     \
  }

  // COMPUTE for matrix m from BUF; epilogue per m. wsel: K<-wk, Q<-wq, V<-wv.
#define COMPUTE(MM, BUF, WSEL, BIAS, DST, TRANSPOSED)                     \
  {                                                                       \
    _Pragma("unroll") for (int t = 0; t < 2; ++t) {                       \
      const uint4* wld = wpk + (WSEL)*32768 + (2 * h + t) * 2048 + half * 32 + l31; \
      f32x16 acc0, acc1;                                                  \
      _Pragma("unroll") for (int r = 0; r < 16; ++r) { acc0[r] = 0.0f; acc1[r] = 0.0f; } \
      _Pragma("unroll 8") for (int k = 0; k < 32; ++k) {                  \
        uint4 b = wld[k * 64];                                            \
        uint4 a0 = ld_lds_64x2((BUF), abase + (unsigned)k * 32);          \
        uint4 a1 = ld_lds_64x2((BUF), XS_BYTES + abase + (unsigned)k * 32);\
        if (TRANSPOSED) {                                                 \
          acc0 = mfma32(b, a0, acc0);                                     \
          acc1 = mfma32(b, a1, acc1);                                     \
        } else {                                                          \
          acc0 = mfma32(a0, b, acc0);                                     \
          acc1 = mfma32(a1, b, acc1);                                     \
        }                                                                 \
      }                                                                   \
      if (TRANSPOSED) {                                                   \
        _Pragma("unroll") for (int q = 0; q < 8; ++q) {                   \
          const int n0 = ((2 * q) & 3) + 8 * (q >> 1) + 4 * half;         \
          float2 bb = *(const float2*)((BIAS) + h * 64 + t * 32 + n0);    \
          DST[0][t][q] = f2b(acc0[2 * q] + bb.x) | (f2b(acc0[2 * q + 1] + bb.y) << 16); \
          DST[1][t][q] = f2b(acc1[2 * q] + bb.x) | (f2b(acc1[2 * q + 1] + bb.y) << 16); \
        }                                                                 \
      } else {                                                            \
        const float bc = (BIAS)[h * 64 + t * 32 + l31];                   \
        _Pragma("unroll") for (int q = 0; q < 8; ++q) {                   \
          DST[0][t][q] = f2b(acc0[2 * q] + bc) | (f2b(acc0[2 * q + 1] + bc) << 16); \
          DST[1][t][q] = f2b(acc1[2 * q] + bc) | (f2b(acc1[2 * q + 1] + bc) << 16); \
        }                                                                 \
      }                                                                   \
    }                                                                     \
  }

  // ---------------- pipelined projections ----------------
  LOADS(k_in);
  WRITE(bufA);
  __syncthreads();

  LOADS(q_in);
  COMPUTE(0, bufA, 1, bk, KT, 1);
  WRITE(bufB);
  __syncthreads();

  LOADS(v_in);
  COMPUTE(1, bufB, 0, bq, QT, 1);
  WRITE(bufA);
  __syncthreads();

  COMPUTE(2, bufA, 2, bv, VP, 0);
  // bufB is dead from here (all waves passed the last barrier after reading it)

  // ---------------- attention per bs (barrier-free, per-wave) ----------------
  asm volatile("" ::: "memory");
  float* scrF = (float*)((char*)bufB + h * 8256);  // per-wave 8256 B region

#pragma unroll
  for (int j = 0; j < 2; ++j) {
    const int bsj = bs0 + j;

    // S^T = K * Q^T : lane = query n, regs = key m
    f32x16 lg;
#pragma unroll
    for (int r = 0; r < 16; ++r) lg[r] = 0.0f;
#pragma unroll
    for (int kk = 0; kk < 4; ++kk) {
      uint4 ka = frag_cd(KT[j][kk >> 1], (kk & 1) * 4, half);
      uint4 qf = frag_cd(QT[j][kk >> 1], (kk & 1) * 4, half);
      lg = mfma32(ka, qf, lg);
    }

    // softmax over keys, in place; additive mask
    const float* mrow = mask + (size_t)bsj * 32;
    float w[16];
#pragma unroll
    for (int q = 0; q < 8; ++q) {
      const int mm0 = ((2 * q) & 3) + 8 * (q >> 1) + 4 * half;
      float2 mk = *(const float2*)(mrow + mm0);
      w[2 * q] = lg[2 * q] * 0.125f + mk.x;
      w[2 * q + 1] = lg[2 * q + 1] * 0.125f + mk.y;
    }
    float mx = w[0];
#pragma unroll
    for (int r = 1; r < 16; ++r) mx = fmaxf(mx, w[r]);
    mx = fmaxf(mx, __shfl_xor(mx, 32));
    float ss = 0.0f;
#pragma unroll
    for (int r = 0; r < 16; ++r) {
      w[r] = __expf(w[r] - mx);
      ss += w[r];
    }
    ss += __shfl_xor(ss, 32);
    const float inv = __frcp_rn(ss);
#pragma unroll
    for (int r = 0; r < 16; ++r) w[r] *= inv;

    // pack P (lane = query n, reg pairs = key rows)
    unsigned PP[8];
#pragma unroll
    for (int q = 0; q < 8; ++q)
      PP[q] = f2b(w[2 * q]) | (f2b(w[2 * q + 1]) << 16);

    // out_w: transpose through per-wave f32 scratch -> 256B-coalesced stores
#pragma unroll
    for (int r = 0; r < 16; ++r) {
      const int mm = (r & 3) + 8 * (r >> 2) + 4 * half;  // key idx
      scrF[l31 * 33 + mm] = w[r];
    }
    const int b = bsj >> 9;
    const int s = bsj & 511;
    float* wout = out_w + ((size_t)((b * 8 + h) * 512 + s)) * 1024;
#pragma unroll
    for (int jj = 0; jj < 16; ++jj) {
      const int n = 2 * jj + half;
      wout[n * 32 + l31] = scrF[n * 33 + l31];
    }

    // O = P * V (all-register)
    f32x16 o0, o1;
#pragma unroll
    for (int r = 0; r < 16; ++r) { o0[r] = 0.0f; o1[r] = 0.0f; }
#pragma unroll
    for (int kk = 0; kk < 2; ++kk) {
      uint4 pa = frag_cd(PP, 4 * kk, half);
      uint4 vb0 = frag_cd(VP[j][0], 4 * kk, half);
      uint4 vb1 = frag_cd(VP[j][1], 4 * kk, half);
      o0 = mfma32(pa, vb0, o0);
      o1 = mfma32(pa, vb1, o1);
    }

    // output: lane col d = t*32+l31 of head h, rows n in regs
    float* obase = out_attn + (size_t)bsj * NBD + h * 64 + l31;
#pragma unroll
    for (int r = 0; r < 16; ++r) {
      const int n = (r & 3) + 8 * (r >> 2) + 4 * half;
      obase[n * 512] = o0[r];
      obase[n * 512 + 32] = o1[r];
    }
  }
#undef LOADS
#undef WRITE
#undef COMPUTE
}

extern "C" void kernel_launch(void* const* d_in, const int* in_sizes, int n_in,
                              void* d_out, int out_size, void* d_ws, size_t ws_size,
                              hipStream_t stream) {
  const float* q    = (const float*)d_in[0];
  const float* k    = (const float*)d_in[1];
  const float* v    = (const float*)d_in[2];
  const float* mask = (const float*)d_in[3];
  const float* wq   = (const float*)d_in[4];
  const float* bq   = (const float*)d_in[5];
  const float* wk   = (const float*)d_in[6];
  const float* bk   = (const float*)d_in[7];
  const float* wv   = (const float*)d_in[8];
  const float* bv   = (const float*)d_in[9];

  uint4* wpk = (uint4*)d_ws;  // 3*32768 uint4 = 1.5 MB fragment-major weights
  float* out_attn = (float*)d_out;
  float* out_w = out_attn + (size_t)4 * 512 * 32 * 512;

  wconv_kernel<<<384, 256, 0, stream>>>(wq, wk, wv, wpk);
  mhba_kernel<<<1024, 512, 0, stream>>>(q, k, v, mask, bq, bk, bv, wpk,
                                        out_attn, out_w);
}

// Round 9
// 245.329 us; speedup vs baseline: 2.5697x; 1.4280x over previous
//
#include <hip/hip_runtime.h>
#include <hip/hip_bf16.h>

// MultiheadBlockAttention: B=4, S=512, NB=32, D=512, H=8, dh=64.
// One WG (8 waves) per (b,s); wave h == head h end-to-end.
// R9 = R8 with the K-phase mode bug fixed: K projections run in NORMAL mode
// (TRANSPOSED=0), matching the normal-mode K epilogue that writes the
// per-wave LDS scratch as [token row][feature col]. (R8 computed K
// transposed -> garbled K -> absmax 3.35.)
// Structure: feature-split double-buffered staging — X staged in two
// 256-feature halves (16.6 KB each); each phase issues the NEXT half's 4
// float4 loads (16 regs in flight), computes 32 MFMAs from the current half,
// writes staged regs, 1 barrier. Global latency hides under compute.

#define NBD (32 * 512)
#define XH_STRIDE 260                   // shorts per half-row = 520 B (2-way free)
#define XH_BYTES (32 * XH_STRIDE * 2)   // 16640 B per half-buffer

typedef __bf16 bf16x8 __attribute__((ext_vector_type(8)));
typedef float f32x16 __attribute__((ext_vector_type(16)));

__device__ __forceinline__ unsigned f2b(float f) {
  union { float f; unsigned u; } v;
  v.f = f;
  return (v.u + 0x7fffu + ((v.u >> 16) & 1u)) >> 16;
}

__device__ __forceinline__ f32x16 mfma32(uint4 a, uint4 b, f32x16 c) {
  union { uint4 u; bf16x8 v; } ua, ub;
  ua.u = a;
  ub.u = b;
  return __builtin_amdgcn_mfma_f32_32x32x16_bf16(ua.v, ub.v, c, 0, 0, 0);
}

// two ds_read_b64 (8-aligned base)
__device__ __forceinline__ uint4 ld_lds_64x2(const unsigned short* p, unsigned byteoff) {
  const char* c = (const char*)p;
  uint2 lo = *(const uint2*)(c + byteoff);
  uint2 hi = *(const uint2*)(c + byteoff + 8);
  uint4 r;
  r.x = lo.x; r.y = lo.y; r.z = hi.x; r.w = hi.y;
  return r;
}

// C/D packed frag -> A/B-frag k-slice [qb block]: cross-half exchange + select.
__device__ __forceinline__ uint4 frag_cd(const unsigned* CP, int qb, int half) {
  const unsigned s0 = __shfl_xor(CP[qb + 0], 32);
  const unsigned s1 = __shfl_xor(CP[qb + 1], 32);
  const unsigned s2 = __shfl_xor(CP[qb + 2], 32);
  const unsigned s3 = __shfl_xor(CP[qb + 3], 32);
  uint4 f;
  f.x = half ? s2 : CP[qb + 0];
  f.y = half ? s3 : CP[qb + 1];
  f.z = half ? CP[qb + 2] : s0;
  f.w = half ? CP[qb + 3] : s1;
  return f;
}

// Pack wq|wk|wv fragment-major bf16: uint4 index
//   m*32768 + tile*2048 + k*64 + half*32 + l31  holds W[tile*32+l31][k*16+half*8..+7]
__global__ void wconv_kernel(const float* __restrict__ wq,
                             const float* __restrict__ wk,
                             const float* __restrict__ wv,
                             uint4* __restrict__ out) {
  const int g = blockIdx.x * blockDim.x + threadIdx.x;  // 0..98303
  const int m = g >> 15;
  const int j = g & 32767;
  const int l31 = j & 31;
  const int half = (j >> 5) & 1;
  const int k = (j >> 6) & 31;
  const int tile = j >> 11;  // 0..15
  const float* src = (m == 0) ? wq : (m == 1) ? wk : wv;
  const float4* p = (const float4*)(src + (size_t)(tile * 32 + l31) * 512 + k * 16 + half * 8);
  float4 f0 = p[0], f1 = p[1];
  uint4 o;
  o.x = f2b(f0.x) | (f2b(f0.y) << 16);
  o.y = f2b(f0.z) | (f2b(f0.w) << 16);
  o.z = f2b(f1.x) | (f2b(f1.y) << 16);
  o.w = f2b(f1.z) | (f2b(f1.w) << 16);
  out[g] = o;
}

__global__ __launch_bounds__(512, 4)
void mhba_kernel(const float* __restrict__ q_in, const float* __restrict__ k_in,
                 const float* __restrict__ v_in, const float* __restrict__ mask,
                 const float* __restrict__ bq, const float* __restrict__ bk,
                 const float* __restrict__ bv,
                 const uint4* __restrict__ wpk,   // fragment-major bf16 weights
                 float* __restrict__ out_attn,    // [B,S,NB,D]
                 float* __restrict__ out_w) {     // [B,H,S,NB,NB]
  __shared__ unsigned short Xs[2][32 * XH_STRIDE];  // 2 x 16640 B half-buffers
  __shared__ __align__(16) char SCR[8][4352];       // 34816 B per-wave scratch

  const int bs = blockIdx.x;    // b = bs>>9, s = bs&511
  const int tid = threadIdx.x;  // 0..511
  const int lane = tid & 63;
  const int h = tid >> 6;       // wave == head
  const int l31 = lane & 31;
  const int half = lane >> 5;

  char* scr = &SCR[h][0];
  const float* srcs[3] = {k_in, q_in, v_in};  // m-order: K, Q, V

  unsigned QT[2][8], VP[2][8];
  const unsigned abase = (unsigned)(l31 * (XH_STRIDE * 2) + half * 16);

  float4 st[4];  // in-flight staging regs (4 float4 = 16 regs)

  // issue the 4 loads for (matrix M, feature-half H1)
#define STAGE_LOAD(M, H1)                                                  \
  {                                                                        \
    const float4* s4 = (const float4*)(srcs[M] + (size_t)bs * NBD);        \
    _Pragma("unroll") for (int i = 0; i < 4; ++i) {                        \
      const int idx4 = i * 512 + tid;                                      \
      st[i] = s4[(idx4 >> 6) * 128 + (H1)*64 + (idx4 & 63)];               \
    }                                                                      \
  }

  // convert + write staged regs into half-buffer P
#define STAGE_WRITE(P)                                                     \
  {                                                                        \
    _Pragma("unroll") for (int i = 0; i < 4; ++i) {                        \
      const int idx4 = i * 512 + tid;                                      \
      const int n = idx4 >> 6, k4 = idx4 & 63;                             \
      uint2 u;                                                             \
      u.x = f2b(st[i].x) | (f2b(st[i].y) << 16);                           \
      u.y = f2b(st[i].z) | (f2b(st[i].w) << 16);                           \
      *(uint2*)((char*)Xs[P] + (n * (XH_STRIDE * 2) + k4 * 8)) = u;        \
    }                                                                      \
  }

  // 16 k-steps x 2 tiles from half-buffer P; acc0 = tile 2h, acc1 = tile 2h+1
#define COMPUTE_HALF(P, WSEL, H1, TRANSPOSED)                              \
  {                                                                        \
    const uint4* w0 = wpk + (WSEL)*32768 + (2 * h) * 2048 + (H1)*1024 +    \
                      half * 32 + l31;                                     \
    const uint4* w1 = w0 + 2048;                                           \
    _Pragma("unroll 8") for (int k = 0; k < 16; ++k) {                     \
      uint4 a = ld_lds_64x2(Xs[P], abase + (unsigned)k * 32);              \
      uint4 b0 = w0[k * 64];                                               \
      uint4 b1 = w1[k * 64];                                               \
      if (TRANSPOSED) {                                                    \
        acc0 = mfma32(b0, a, acc0);                                        \
        acc1 = mfma32(b1, a, acc1);                                        \
      } else {                                                             \
        acc0 = mfma32(a, b0, acc0);                                        \
        acc1 = mfma32(a, b1, acc1);                                        \
      }                                                                    \
    }                                                                      \
  }

  f32x16 acc0, acc1;
#pragma unroll
  for (int r = 0; r < 16; ++r) { acc0[r] = 0.0f; acc1[r] = 0.0f; }

  // ---------------- pipelined projections (7 phases, 6 barriers) ----------
  STAGE_LOAD(0, 0);
  STAGE_WRITE(0);
  __syncthreads();

  // ph0: K half0 from buf0 (NORMAL mode), stage K half1 -> buf1
  STAGE_LOAD(0, 1);
  COMPUTE_HALF(0, 1, 0, 0);
  STAGE_WRITE(1);
  __syncthreads();

  // ph1: K half1 from buf1 (NORMAL mode), stage Q half0 -> buf0
  STAGE_LOAD(1, 0);
  COMPUTE_HALF(1, 1, 1, 0);
  {  // K epilogue (normal C/D: lane = feature col, regs = token rows)
    const float bc0 = bk[h * 64 + l31];
    const float bc1 = bk[h * 64 + 32 + l31];
#pragma unroll
    for (int r = 0; r < 16; ++r) {
      const int n = (r & 3) + 8 * (r >> 2) + 4 * half;
      const unsigned base = (unsigned)(n * 128);
      const unsigned sw = (unsigned)(n & 7) << 4;
      *(unsigned short*)(scr + ((base + l31 * 2) ^ sw)) =
          (unsigned short)f2b(acc0[r] + bc0);
      *(unsigned short*)(scr + ((base + 64 + l31 * 2) ^ sw)) =
          (unsigned short)f2b(acc1[r] + bc1);
      acc0[r] = 0.0f;
      acc1[r] = 0.0f;
    }
  }
  STAGE_WRITE(0);
  __syncthreads();

  // ph2: Q half0 from buf0 (transposed), stage Q half1 -> buf1
  STAGE_LOAD(1, 1);
  COMPUTE_HALF(0, 0, 0, 1);
  STAGE_WRITE(1);
  __syncthreads();

  // ph3: Q half1 from buf1 (transposed), stage V half0 -> buf0
  STAGE_LOAD(2, 0);
  COMPUTE_HALF(1, 0, 1, 1);
  {  // Q^T epilogue: lane = token, regs = features
#pragma unroll
    for (int q = 0; q < 8; ++q) {
      const int n0 = ((2 * q) & 3) + 8 * (q >> 1) + 4 * half;  // feature idx
      float2 bv0 = *(const float2*)(bq + h * 64 + n0);
      float2 bv1 = *(const float2*)(bq + h * 64 + 32 + n0);
      QT[0][q] = f2b(acc0[2 * q] + bv0.x) | (f2b(acc0[2 * q + 1] + bv0.y) << 16);
      QT[1][q] = f2b(acc1[2 * q] + bv1.x) | (f2b(acc1[2 * q + 1] + bv1.y) << 16);
      acc0[2 * q] = 0.0f; acc0[2 * q + 1] = 0.0f;
      acc1[2 * q] = 0.0f; acc1[2 * q + 1] = 0.0f;
    }
  }
  STAGE_WRITE(0);
  __syncthreads();

  // ph4: V half0 from buf0 (normal), stage V half1 -> buf1
  STAGE_LOAD(2, 1);
  COMPUTE_HALF(0, 2, 0, 0);
  STAGE_WRITE(1);
  __syncthreads();

  // ph5: V half1 from buf1 (normal, no staging)
  COMPUTE_HALF(1, 2, 1, 0);
  {  // V epilogue: lane = feature col, regs = token rows
    const float bc0 = bv[h * 64 + l31];
    const float bc1 = bv[h * 64 + 32 + l31];
#pragma unroll
    for (int q = 0; q < 8; ++q) {
      VP[0][q] = f2b(acc0[2 * q] + bc0) | (f2b(acc0[2 * q + 1] + bc0) << 16);
      VP[1][q] = f2b(acc1[2 * q] + bc1) | (f2b(acc1[2 * q + 1] + bc1) << 16);
    }
  }

  // ---------------- attention (barrier-free, per-wave; R5 verbatim) -------
  // K A-frags from scratch
  uint4 KA[4];
#pragma unroll
  for (int kk = 0; kk < 4; ++kk) {
    const unsigned off =
        (unsigned)(l31 * 128 + kk * 32 + half * 16) ^ ((unsigned)(l31 & 7) << 4);
    KA[kk] = *(const uint4*)(scr + off);
  }

  // S^T = K * Q^T : lane = query n, regs = key m
  f32x16 lg;
#pragma unroll
  for (int r = 0; r < 16; ++r) lg[r] = 0.0f;
#pragma unroll
  for (int kk = 0; kk < 4; ++kk) {
    uint4 qf = frag_cd(QT[kk >> 1], (kk & 1) * 4, half);
    lg = mfma32(KA[kk], qf, lg);
  }

  // softmax over keys m, in place (lane = query n, regs = key m)
  const float* mrow = mask + (size_t)bs * 32;
  float w[16];
#pragma unroll
  for (int q = 0; q < 8; ++q) {
    const int mm0 = ((2 * q) & 3) + 8 * (q >> 1) + 4 * half;
    float2 mk = *(const float2*)(mrow + mm0);
    w[2 * q] = lg[2 * q] * 0.125f + mk.x;
    w[2 * q + 1] = lg[2 * q + 1] * 0.125f + mk.y;
  }
  float mx = w[0];
#pragma unroll
  for (int r = 1; r < 16; ++r) mx = fmaxf(mx, w[r]);
  mx = fmaxf(mx, __shfl_xor(mx, 32));
  float ss = 0.0f;
#pragma unroll
  for (int r = 0; r < 16; ++r) {
    w[r] = __expf(w[r] - mx);
    ss += w[r];
  }
  ss += __shfl_xor(ss, 32);
  const float inv = __frcp_rn(ss);
#pragma unroll
  for (int r = 0; r < 16; ++r) w[r] *= inv;

  // pack P (lane = query n, reg pairs = key rows)
  unsigned PP[8];
#pragma unroll
  for (int q = 0; q < 8; ++q)
    PP[q] = f2b(w[2 * q]) | (f2b(w[2 * q + 1]) << 16);

  // out_w: transpose through per-wave scratch (f32 view; K-buf dead by data dep)
  asm volatile("" ::: "memory");
  float* scrF = (float*)scr;  // 32 x 33 floats = 4224 B
#pragma unroll
  for (int r = 0; r < 16; ++r) {
    const int mm = (r & 3) + 8 * (r >> 2) + 4 * half;
    scrF[l31 * 33 + mm] = w[r];  // [query n=l31][key mm]
  }
  const int b = bs >> 9;
  const int s = bs & 511;
  float* wout = out_w + ((size_t)((b * 8 + h) * 512 + s)) * 1024;
#pragma unroll
  for (int j = 0; j < 16; ++j) {
    const int n = 2 * j + half;
    wout[n * 32 + l31] = scrF[n * 33 + l31];
  }

  // O = P * V
  f32x16 o0, o1;
#pragma unroll
  for (int r = 0; r < 16; ++r) { o0[r] = 0.0f; o1[r] = 0.0f; }
#pragma unroll
  for (int kk = 0; kk < 2; ++kk) {
    uint4 pa = frag_cd(PP, 4 * kk, half);
    uint4 vb0 = frag_cd(VP[0], 4 * kk, half);
    uint4 vb1 = frag_cd(VP[1], 4 * kk, half);
    o0 = mfma32(pa, vb0, o0);
    o1 = mfma32(pa, vb1, o1);
  }

  // output: lane col d = t*32+l31 of head h, rows n in regs
  float* obase = out_attn + (size_t)bs * NBD + h * 64 + l31;
#pragma unroll
  for (int r = 0; r < 16; ++r) {
    const int n = (r & 3) + 8 * (r >> 2) + 4 * half;
    obase[n * 512] = o0[r];
    obase[n * 512 + 32] = o1[r];
  }
#undef STAGE_LOAD
#undef STAGE_WRITE
#undef COMPUTE_HALF
}

extern "C" void kernel_launch(void* const* d_in, const int* in_sizes, int n_in,
                              void* d_out, int out_size, void* d_ws, size_t ws_size,
                              hipStream_t stream) {
  const float* q    = (const float*)d_in[0];
  const float* k    = (const float*)d_in[1];
  const float* v    = (const float*)d_in[2];
  const float* mask = (const float*)d_in[3];
  const float* wq   = (const float*)d_in[4];
  const float* bq   = (const float*)d_in[5];
  const float* wk   = (const float*)d_in[6];
  const float* bk   = (const float*)d_in[7];
  const float* wv   = (const float*)d_in[8];
  const float* bv   = (const float*)d_in[9];

  uint4* wpk = (uint4*)d_ws;  // 3*32768 uint4 = 1.5 MB fragment-major weights
  float* out_attn = (float*)d_out;
  float* out_w = out_attn + (size_t)4 * 512 * 32 * 512;

  wconv_kernel<<<384, 256, 0, stream>>>(wq, wk, wv, wpk);
  mhba_kernel<<<2048, 512, 0, stream>>>(q, k, v, mask, bq, bk, bv, wpk,
                                        out_attn, out_w);
}

// Round 10
// 232.588 us; speedup vs baseline: 2.7105x; 1.0548x over previous
//
#include <hip/hip_runtime.h>
#include <hip/hip_bf16.h>

// MultiheadBlockAttention: B=4, S=512, NB=32, D=512, H=8, dh=64.
// R10: SMUL=2 at launch_bounds(512,2) — 256 unified regs, 1 WG/CU.
// One WG (8 waves) = TWO (b,s); wave h == head h. Each weight fragment load
// feeds 4 MFMAs (2 bs x 2 tiles) -> halves R5's 89us per-XCD L2 weight
// stream. Register plan (spill lessons R4/R6/R7/R9):
//   persistent QT/VP (64) + 4 accs (64 AGPR) + lean st[8] staging (32) ~ 185.
// K goes to per-wave LDS scratch (2 x 4352 B per wave); feature-split
// double-buffered X staging (R9-proven phase structure, both bs per buffer).

#define NBD (32 * 512)
#define XH_STRIDE 260                   // shorts per half-row = 520 B
#define XH_BYTES (32 * XH_STRIDE * 2)   // 16640 B per (bs) half-slice

typedef __bf16 bf16x8 __attribute__((ext_vector_type(8)));
typedef float f32x16 __attribute__((ext_vector_type(16)));

__device__ __forceinline__ unsigned f2b(float f) {
  union { float f; unsigned u; } v;
  v.f = f;
  return (v.u + 0x7fffu + ((v.u >> 16) & 1u)) >> 16;
}

__device__ __forceinline__ f32x16 mfma32(uint4 a, uint4 b, f32x16 c) {
  union { uint4 u; bf16x8 v; } ua, ub;
  ua.u = a;
  ub.u = b;
  return __builtin_amdgcn_mfma_f32_32x32x16_bf16(ua.v, ub.v, c, 0, 0, 0);
}

// two ds_read_b64 (8-aligned base)
__device__ __forceinline__ uint4 ld_lds_64x2(const unsigned short* p, unsigned byteoff) {
  const char* c = (const char*)p;
  uint2 lo = *(const uint2*)(c + byteoff);
  uint2 hi = *(const uint2*)(c + byteoff + 8);
  uint4 r;
  r.x = lo.x; r.y = lo.y; r.z = hi.x; r.w = hi.y;
  return r;
}

// C/D packed frag -> A/B-frag k-slice [qb block]: cross-half exchange + select.
__device__ __forceinline__ uint4 frag_cd(const unsigned* CP, int qb, int half) {
  const unsigned s0 = __shfl_xor(CP[qb + 0], 32);
  const unsigned s1 = __shfl_xor(CP[qb + 1], 32);
  const unsigned s2 = __shfl_xor(CP[qb + 2], 32);
  const unsigned s3 = __shfl_xor(CP[qb + 3], 32);
  uint4 f;
  f.x = half ? s2 : CP[qb + 0];
  f.y = half ? s3 : CP[qb + 1];
  f.z = half ? CP[qb + 2] : s0;
  f.w = half ? CP[qb + 3] : s1;
  return f;
}

// Pack wq|wk|wv fragment-major bf16: uint4 index
//   m*32768 + tile*2048 + k*64 + half*32 + l31  holds W[tile*32+l31][k*16+half*8..+7]
__global__ void wconv_kernel(const float* __restrict__ wq,
                             const float* __restrict__ wk,
                             const float* __restrict__ wv,
                             uint4* __restrict__ out) {
  const int g = blockIdx.x * blockDim.x + threadIdx.x;  // 0..98303
  const int m = g >> 15;
  const int j = g & 32767;
  const int l31 = j & 31;
  const int half = (j >> 5) & 1;
  const int k = (j >> 6) & 31;
  const int tile = j >> 11;  // 0..15
  const float* src = (m == 0) ? wq : (m == 1) ? wk : wv;
  const float4* p = (const float4*)(src + (size_t)(tile * 32 + l31) * 512 + k * 16 + half * 8);
  float4 f0 = p[0], f1 = p[1];
  uint4 o;
  o.x = f2b(f0.x) | (f2b(f0.y) << 16);
  o.y = f2b(f0.z) | (f2b(f0.w) << 16);
  o.z = f2b(f1.x) | (f2b(f1.y) << 16);
  o.w = f2b(f1.z) | (f2b(f1.w) << 16);
  out[g] = o;
}

__global__ __launch_bounds__(512, 2)
void mhba_kernel(const float* __restrict__ q_in, const float* __restrict__ k_in,
                 const float* __restrict__ v_in, const float* __restrict__ mask,
                 const float* __restrict__ bq, const float* __restrict__ bk,
                 const float* __restrict__ bv,
                 const uint4* __restrict__ wpk,   // fragment-major bf16 weights
                 float* __restrict__ out_attn,    // [B,S,NB,D]
                 float* __restrict__ out_w) {     // [B,H,S,NB,NB]
  // Half-buffers hold BOTH bs slices: [buf][bs j at j*XH_BYTES].
  __shared__ unsigned short Xs[2][2 * 32 * XH_STRIDE];  // 66560 B
  __shared__ __align__(16) char SCR[8][2][4352];        // 69632 B

  const int bs0 = blockIdx.x * 2;
  const int tid = threadIdx.x;  // 0..511
  const int lane = tid & 63;
  const int h = tid >> 6;       // wave == head
  const int l31 = lane & 31;
  const int half = lane >> 5;

  const float* srcs[3] = {k_in, q_in, v_in};  // m-order: K, Q, V

  unsigned QT[2][2][8], VP[2][2][8];  // [bs j][tile t][q]
  const unsigned abase = (unsigned)(l31 * (XH_STRIDE * 2) + half * 16);

  float4 st[8];  // in-flight staging regs (2 bs x 4 float4)

  // issue the 8 loads for (matrix M, feature-half H1), both bs
#define STAGE_LOAD(M, H1)                                                  \
  {                                                                        \
    _Pragma("unroll") for (int j = 0; j < 2; ++j) {                        \
      const float4* s4 = (const float4*)(srcs[M] + (size_t)(bs0 + j) * NBD);\
      _Pragma("unroll") for (int i = 0; i < 4; ++i) {                      \
        const int idx4 = i * 512 + tid;                                    \
        st[j * 4 + i] = s4[(idx4 >> 6) * 128 + (H1)*64 + (idx4 & 63)];     \
      }                                                                    \
    }                                                                      \
  }

  // convert + write staged regs into half-buffer P (both bs)
#define STAGE_WRITE(P)                                                     \
  {                                                                        \
    _Pragma("unroll") for (int j = 0; j < 2; ++j) {                        \
      _Pragma("unroll") for (int i = 0; i < 4; ++i) {                      \
        const int idx4 = i * 512 + tid;                                    \
        const int n = idx4 >> 6, k4 = idx4 & 63;                           \
        float4 f = st[j * 4 + i];                                          \
        uint2 u;                                                           \
        u.x = f2b(f.x) | (f2b(f.y) << 16);                                 \
        u.y = f2b(f.z) | (f2b(f.w) << 16);                                 \
        *(uint2*)((char*)Xs[P] + (j * XH_BYTES + n * (XH_STRIDE * 2) + k4 * 8)) = u; \
      }                                                                    \
    }                                                                      \
  }

  // 16 k-steps from half-buffer P; weight frags shared across bs ->
  // 4 MFMAs per 2 weight loads. accJT: bs j, tile t.
#define COMPUTE_HALF(P, WSEL, H1, TRANSPOSED)                              \
  {                                                                        \
    const uint4* w0 = wpk + (WSEL)*32768 + (2 * h) * 2048 + (H1)*1024 +    \
                      half * 32 + l31;                                     \
    const uint4* w1 = w0 + 2048;                                           \
    _Pragma("unroll 4") for (int k = 0; k < 16; ++k) {                     \
      uint4 b0 = w0[k * 64];                                               \
      uint4 b1 = w1[k * 64];                                               \
      uint4 a0 = ld_lds_64x2(Xs[P], abase + (unsigned)k * 32);             \
      uint4 a1 = ld_lds_64x2(Xs[P], XH_BYTES + abase + (unsigned)k * 32);  \
      if (TRANSPOSED) {                                                    \
        acc00 = mfma32(b0, a0, acc00);                                     \
        acc01 = mfma32(b1, a0, acc01);                                     \
        acc10 = mfma32(b0, a1, acc10);                                     \
        acc11 = mfma32(b1, a1, acc11);                                     \
      } else {                                                             \
        acc00 = mfma32(a0, b0, acc00);                                     \
        acc01 = mfma32(a0, b1, acc01);                                     \
        acc10 = mfma32(a1, b0, acc10);                                     \
        acc11 = mfma32(a1, b1, acc11);                                     \
      }                                                                    \
    }                                                                      \
  }

#define RESET_ACCS                                                         \
  {                                                                        \
    _Pragma("unroll") for (int r = 0; r < 16; ++r) {                       \
      acc00[r] = 0.0f; acc01[r] = 0.0f; acc10[r] = 0.0f; acc11[r] = 0.0f;  \
    }                                                                      \
  }

  f32x16 acc00, acc01, acc10, acc11;
  RESET_ACCS;

  // ---------------- pipelined projections (R9 phase structure) ------------
  STAGE_LOAD(0, 0);
  STAGE_WRITE(0);
  __syncthreads();

  // ph0: K half0 from buf0 (NORMAL), stage K half1 -> buf1
  STAGE_LOAD(0, 1);
  COMPUTE_HALF(0, 1, 0, 0);
  STAGE_WRITE(1);
  __syncthreads();

  // ph1: K half1 from buf1 (NORMAL), stage Q half0 -> buf0
  STAGE_LOAD(1, 0);
  COMPUTE_HALF(1, 1, 1, 0);
  {  // K epilogue per bs (normal C/D: lane = feature col, regs = token rows)
    const float bc0 = bk[h * 64 + l31];
    const float bc1 = bk[h * 64 + 32 + l31];
#pragma unroll
    for (int j = 0; j < 2; ++j) {
      char* scr = &SCR[h][j][0];
#pragma unroll
      for (int r = 0; r < 16; ++r) {
        const int n = (r & 3) + 8 * (r >> 2) + 4 * half;
        const unsigned base = (unsigned)(n * 128);
        const unsigned sw = (unsigned)(n & 7) << 4;
        const float a0 = (j == 0) ? acc00[r] : acc10[r];
        const float a1 = (j == 0) ? acc01[r] : acc11[r];
        *(unsigned short*)(scr + ((base + l31 * 2) ^ sw)) =
            (unsigned short)f2b(a0 + bc0);
        *(unsigned short*)(scr + ((base + 64 + l31 * 2) ^ sw)) =
            (unsigned short)f2b(a1 + bc1);
      }
    }
    RESET_ACCS;
  }
  STAGE_WRITE(0);
  __syncthreads();

  // ph2: Q half0 from buf0 (TRANSPOSED), stage Q half1 -> buf1
  STAGE_LOAD(1, 1);
  COMPUTE_HALF(0, 0, 0, 1);
  STAGE_WRITE(1);
  __syncthreads();

  // ph3: Q half1 from buf1 (TRANSPOSED), stage V half0 -> buf0
  STAGE_LOAD(2, 0);
  COMPUTE_HALF(1, 0, 1, 1);
  {  // Q^T epilogue: lane = token, regs = features
#pragma unroll
    for (int q = 0; q < 8; ++q) {
      const int n0 = ((2 * q) & 3) + 8 * (q >> 1) + 4 * half;  // feature idx
      float2 b0 = *(const float2*)(bq + h * 64 + n0);
      float2 b1 = *(const float2*)(bq + h * 64 + 32 + n0);
      QT[0][0][q] = f2b(acc00[2 * q] + b0.x) | (f2b(acc00[2 * q + 1] + b0.y) << 16);
      QT[0][1][q] = f2b(acc01[2 * q] + b1.x) | (f2b(acc01[2 * q + 1] + b1.y) << 16);
      QT[1][0][q] = f2b(acc10[2 * q] + b0.x) | (f2b(acc10[2 * q + 1] + b0.y) << 16);
      QT[1][1][q] = f2b(acc11[2 * q] + b1.x) | (f2b(acc11[2 * q + 1] + b1.y) << 16);
    }
    RESET_ACCS;
  }
  STAGE_WRITE(0);
  __syncthreads();

  // ph4: V half0 from buf0 (NORMAL), stage V half1 -> buf1
  STAGE_LOAD(2, 1);
  COMPUTE_HALF(0, 2, 0, 0);
  STAGE_WRITE(1);
  __syncthreads();

  // ph5: V half1 from buf1 (NORMAL, no staging)
  COMPUTE_HALF(1, 2, 1, 0);
  {  // V epilogue: lane = feature col, regs = token rows
    const float bc0 = bv[h * 64 + l31];
    const float bc1 = bv[h * 64 + 32 + l31];
#pragma unroll
    for (int q = 0; q < 8; ++q) {
      VP[0][0][q] = f2b(acc00[2 * q] + bc0) | (f2b(acc00[2 * q + 1] + bc0) << 16);
      VP[0][1][q] = f2b(acc01[2 * q] + bc1) | (f2b(acc01[2 * q + 1] + bc1) << 16);
      VP[1][0][q] = f2b(acc10[2 * q] + bc0) | (f2b(acc10[2 * q + 1] + bc0) << 16);
      VP[1][1][q] = f2b(acc11[2 * q] + bc1) | (f2b(acc11[2 * q + 1] + bc1) << 16);
    }
  }

  // ---------------- attention per bs (barrier-free, per-wave) -------------
#pragma unroll
  for (int j = 0; j < 2; ++j) {
    const int bsj = bs0 + j;
    char* scr = &SCR[h][j][0];

    // K A-frags from scratch
    uint4 KA[4];
#pragma unroll
    for (int kk = 0; kk < 4; ++kk) {
      const unsigned off =
          (unsigned)(l31 * 128 + kk * 32 + half * 16) ^ ((unsigned)(l31 & 7) << 4);
      KA[kk] = *(const uint4*)(scr + off);
    }

    // S^T = K * Q^T : lane = query n, regs = key m
    f32x16 lg;
#pragma unroll
    for (int r = 0; r < 16; ++r) lg[r] = 0.0f;
#pragma unroll
    for (int kk = 0; kk < 4; ++kk) {
      uint4 qf = frag_cd(QT[j][kk >> 1], (kk & 1) * 4, half);
      lg = mfma32(KA[kk], qf, lg);
    }

    // softmax over keys m, in place; additive mask
    const float* mrow = mask + (size_t)bsj * 32;
    float w[16];
#pragma unroll
    for (int q = 0; q < 8; ++q) {
      const int mm0 = ((2 * q) & 3) + 8 * (q >> 1) + 4 * half;
      float2 mk = *(const float2*)(mrow + mm0);
      w[2 * q] = lg[2 * q] * 0.125f + mk.x;
      w[2 * q + 1] = lg[2 * q + 1] * 0.125f + mk.y;
    }
    float mx = w[0];
#pragma unroll
    for (int r = 1; r < 16; ++r) mx = fmaxf(mx, w[r]);
    mx = fmaxf(mx, __shfl_xor(mx, 32));
    float ss = 0.0f;
#pragma unroll
    for (int r = 0; r < 16; ++r) {
      w[r] = __expf(w[r] - mx);
      ss += w[r];
    }
    ss += __shfl_xor(ss, 32);
    const float inv = __frcp_rn(ss);
#pragma unroll
    for (int r = 0; r < 16; ++r) w[r] *= inv;

    // pack P (lane = query n, reg pairs = key rows)
    unsigned PP[8];
#pragma unroll
    for (int q = 0; q < 8; ++q)
      PP[q] = f2b(w[2 * q]) | (f2b(w[2 * q + 1]) << 16);

    // out_w: transpose through scratch j (K-buf dead by data dependence)
    asm volatile("" ::: "memory");
    float* scrF = (float*)scr;  // 32 x 33 floats = 4224 B <= 4352
#pragma unroll
    for (int r = 0; r < 16; ++r) {
      const int mm = (r & 3) + 8 * (r >> 2) + 4 * half;
      scrF[l31 * 33 + mm] = w[r];  // [query n=l31][key mm]
    }
    const int b = bsj >> 9;
    const int s = bsj & 511;
    float* wout = out_w + ((size_t)((b * 8 + h) * 512 + s)) * 1024;
#pragma unroll
    for (int jj = 0; jj < 16; ++jj) {
      const int n = 2 * jj + half;
      wout[n * 32 + l31] = scrF[n * 33 + l31];
    }

    // O = P * V
    f32x16 o0, o1;
#pragma unroll
    for (int r = 0; r < 16; ++r) { o0[r] = 0.0f; o1[r] = 0.0f; }
#pragma unroll
    for (int kk = 0; kk < 2; ++kk) {
      uint4 pa = frag_cd(PP, 4 * kk, half);
      uint4 vb0 = frag_cd(VP[j][0], 4 * kk, half);
      uint4 vb1 = frag_cd(VP[j][1], 4 * kk, half);
      o0 = mfma32(pa, vb0, o0);
      o1 = mfma32(pa, vb1, o1);
    }

    // output: lane col d = t*32+l31 of head h, rows n in regs
    float* obase = out_attn + (size_t)bsj * NBD + h * 64 + l31;
#pragma unroll
    for (int r = 0; r < 16; ++r) {
      const int n = (r & 3) + 8 * (r >> 2) + 4 * half;
      obase[n * 512] = o0[r];
      obase[n * 512 + 32] = o1[r];
    }
  }
#undef STAGE_LOAD
#undef STAGE_WRITE
#undef COMPUTE_HALF
#undef RESET_ACCS
}

extern "C" void kernel_launch(void* const* d_in, const int* in_sizes, int n_in,
                              void* d_out, int out_size, void* d_ws, size_t ws_size,
                              hipStream_t stream) {
  const float* q    = (const float*)d_in[0];
  const float* k    = (const float*)d_in[1];
  const float* v    = (const float*)d_in[2];
  const float* mask = (const float*)d_in[3];
  const float* wq   = (const float*)d_in[4];
  const float* bq   = (const float*)d_in[5];
  const float* wk   = (const float*)d_in[6];
  const float* bk   = (const float*)d_in[7];
  const float* wv   = (const float*)d_in[8];
  const float* bv   = (const float*)d_in[9];

  uint4* wpk = (uint4*)d_ws;  // 3*32768 uint4 = 1.5 MB fragment-major weights
  float* out_attn = (float*)d_out;
  float* out_w = out_attn + (size_t)4 * 512 * 32 * 512;

  wconv_kernel<<<384, 256, 0, stream>>>(wq, wk, wv, wpk);
  mhba_kernel<<<1024, 512, 0, stream>>>(q, k, v, mask, bq, bk, bv, wpk,
                                        out_attn, out_w);
}